// Round 8
// baseline (5831.065 us; speedup 1.0000x reference)
//
#include <hip/hip_runtime.h>
#include <hip/hip_bf16.h>

typedef __hip_bfloat16 bf16;
typedef __attribute__((ext_vector_type(8))) short v8bf;     // 8 bf16 (4 VGPR)
typedef __attribute__((ext_vector_type(16))) float f32x16;
typedef __attribute__((ext_vector_type(4))) float f32x4;

#define B_    256
#define SEED_ 120
#define PRED_ 24
#define D_    126
#define H_    1024
#define F_    61
#define HEADS_ 4
#define DH_   256

#define GLD16(lds, g) __builtin_amdgcn_global_load_lds( \
    (const __attribute__((address_space(1))) unsigned int*)(g), \
    (__attribute__((address_space(3))) unsigned int*)(lds), 16, 0, 0)
#define VMWAIT(n) asm volatile("s_waitcnt vmcnt(" #n ")" ::: "memory")
#define BARRIER() do { __builtin_amdgcn_s_barrier(); __builtin_amdgcn_sched_barrier(0); } while(0)

__device__ inline v8bf u2v(uint4 x){ union { uint4 u; v8bf v; } c; c.u = x; return c.v; }

// ---------------- small precompute kernels ----------------
__global__ void k_cos(float* cosT){
  int i = blockIdx.x*256 + threadIdx.x;
  if (i < F_*SEED_){
    int f = i / SEED_, t = i % SEED_;
    int ph = (f*t) % SEED_;
    cosT[i] = cosf(6.283185307179586f * (float)ph / (float)SEED_);
  }
}

// one block per b; poses row staged once in LDS; 31 f-accumulators per thread.
__global__ __launch_bounds__(256) void k_dft2(const float* __restrict__ poses,
                      const float* __restrict__ cosT, bf16* __restrict__ freqbf){
  __shared__ float pl[SEED_*128];      // 60 KB
  int b = blockIdx.x, tid = threadIdx.x;
  for (int i = tid; i < SEED_*D_; i += 256){
    int t = i / D_, d = i - t*D_;
    pl[t*128 + d] = poses[((size_t)b*(SEED_+PRED_) + t)*D_ + d];
  }
  __syncthreads();
  int d = tid & 127, f0 = tid >> 7;    // f = f0 + 2j
  float acc[31];
  #pragma unroll
  for (int j = 0; j < 31; ++j) acc[j] = 0.f;
  for (int t = 0; t < SEED_; ++t){
    float v = pl[t*128 + d];
    #pragma unroll
    for (int j = 0; j < 31; ++j){
      int f = f0 + j*2;
      if (f < F_) acc[j] += cosT[f*SEED_ + t] * v;
    }
  }
  #pragma unroll
  for (int j = 0; j < 31; ++j){
    int f = f0 + j*2;
    if (f < F_) freqbf[((size_t)b*F_ + f)*128 + d] = __float2bfloat16(d < D_ ? acc[j] : 0.f);
  }
}

// pack poses into per-step 32x32 tiles: pk[t][ (b>>5)*4 + (c>>5) ][ (b&31)*32 + (c&31) ]
__global__ void c_poses(const float* __restrict__ poses, bf16* __restrict__ pk){
  int t = blockIdx.x, b = blockIdx.y, c = threadIdx.x;  // block 128
  float v = (c < D_) ? poses[((size_t)b*(SEED_+PRED_) + t)*D_ + c] : 0.f;
  pk[(size_t)t*32768 + ((b>>5)*4 + (c>>5))*1024 + (b&31)*32 + (c&31)] = __float2bfloat16(v);
}

__global__ void c_xinit(const float* __restrict__ poses, float* __restrict__ x, bf16* __restrict__ xpk){
  int b = blockIdx.x, c = threadIdx.x;  // block 128
  float v = (c < D_) ? poses[((size_t)b*(SEED_+PRED_) + (SEED_-1))*D_ + c] : 0.f;
  if (c < D_) x[b*D_ + c] = v;
  xpk[((b>>5)*4 + (c>>5))*1024 + (b&31)*32 + (c&31)] = __float2bfloat16(v);
}

__global__ void c_bf(const float* __restrict__ s, bf16* __restrict__ d, int n){
  int i = blockIdx.x*256 + threadIdx.x;
  if (i < n) d[i] = __float2bfloat16(s[i]);
}

__global__ void c_fpwt(const float* __restrict__ fpW, bf16* __restrict__ o){
  int dd = blockIdx.x;                       // 0..127
  for (int k = threadIdx.x; k < H_; k += 256)
    o[(size_t)dd*H_ + k] = __float2bfloat16(dd < D_ ? fpW[(size_t)k*D_ + dd] : 0.f);
}

__global__ void c_w1hid(const float* __restrict__ W1, bf16* __restrict__ o){
  int i = blockIdx.x*256 + threadIdx.x;      // 1792*1024
  if (i < 1792*1024){ int r = i >> 10, c = i & 1023; o[i] = __float2bfloat16(W1[(size_t)r*1033 + c]); }
}

// combined GRU weight: rows 0..1023=[Wih_r|Whh_r]; 1024..2047=[Wih_z|Whh_z];
// 2048..3071=[Wih_n|0]; 3072..4095=[0|Whh_n]  (row width 1152 = 128 x | 1024 h)
__global__ void c_wcat(const float* __restrict__ Wih, const float* __restrict__ Whh, bf16* __restrict__ o){
  int r = blockIdx.x;
  int jr; bool hasx, hash;
  if (r < 2048){ jr = r; hasx = true; hash = true; }
  else if (r < 3072){ jr = r; hasx = true; hash = false; }
  else { jr = r - 1024; hasx = false; hash = true; }
  bf16* row = o + (size_t)r*1152;
  for (int c = threadIdx.x; c < 1152; c += 256){
    float v = 0.f;
    if (c < D_) { if (hasx) v = Wih[(size_t)jr*D_ + c]; }
    else if (c >= 128){ if (hash) v = Whh[(size_t)jr*H_ + (c-128)]; }
    row[c] = __float2bfloat16(v);
  }
}

__global__ void c_bcat(const float* __restrict__ bih, const float* __restrict__ bhh, float* __restrict__ o){
  int r = blockIdx.x*256 + threadIdx.x;
  if (r >= 4096) return;
  float v;
  if (r < 2048) v = bih[r] + bhh[r];
  else if (r < 3072) v = bih[r];
  else v = bhh[r - 1024];
  o[r] = v;
}

// pack GRU weights into MFMA B-fragment order:
// chunk = ((ub*3+g)*36+ks): elem[l*8+e] = W_g[ub*16+(l&15)][ks*32+(l>>4)*8+e]
__global__ __launch_bounds__(256) void c_wpk(const bf16* __restrict__ Wcat, bf16* __restrict__ Wpk){
  int chunk = blockIdx.x*4 + (threadIdx.x >> 6);
  int l = threadIdx.x & 63;
  int ks = chunk % 36; int t2 = chunk / 36; int g = t2 % 3; int ub = t2 / 3;
  int unit = ub*16 + (l & 15);
  bf16* dst = Wpk + (size_t)chunk*512 + l*8;
  #pragma unroll
  for (int e = 0; e < 8; ++e){
    int k = ks*32 + (l>>4)*8 + e;
    int row = (g==0) ? unit : (g==1) ? (1024+unit) : (k < 128 ? 2048+unit : 3072+unit);
    dst[e] = Wcat[(size_t)row*1152 + k];
  }
}

// bc = inproj @ fp_b + in_b : wave-per-row float4 reduction. grid 768, block 256.
__global__ __launch_bounds__(256) void k_bc(const float* __restrict__ inW, const float* __restrict__ inb,
                     const float* __restrict__ fpb, float* __restrict__ bc){
  int wave = threadIdx.x >> 6, lane = threadIdx.x & 63;
  int r = blockIdx.x*4 + wave;
  const float4* row = (const float4*)(inW + (size_t)r*H_);
  const float4* fp4 = (const float4*)fpb;
  float s = 0.f;
  #pragma unroll
  for (int i = 0; i < 4; ++i){
    float4 a = row[lane + i*64];
    float4 b = fp4[lane + i*64];
    s += a.x*b.x + a.y*b.y + a.z*b.z + a.w*b.w;
  }
  #pragma unroll
  for (int off = 32; off; off >>= 1) s += __shfl_down(s, off);
  if (lane == 0) bc[r] = s + inb[r];
}

// ---------------- wave-autonomous GRU with producer/consumer flags ----------------
// grid 256 = 64 unit-slices (ub) x 4 batch quarters (q); block 128 (2 waves x 32 rows).
// Weights LDS-resident (108KB). A: global->VGPR, ring of 12 slices x 2 sub-fragments.
// Sync (encoder): prog[q*64+ub] monotonic counter; consumer spins on 64 acquire-loads
// (its quarter's producers) -- producers of a block's rows are exactly its readers,
// so 2 ping-pong h buffers are race-free (flag provides backpressure).
#define SLC2(QA, QB, KS, G2A, G2B) { \
  v8bf a0_ = u2v(QA), a1_ = u2v(QB); \
  const int wo_ = (KS)*512 + lane*8; \
  v8bf w0_ = *(const v8bf*)&Wl[wo_]; \
  v8bf w1_ = *(const v8bf*)&Wl[18432 + wo_]; \
  v8bf w2_ = *(const v8bf*)&Wl[36864 + wo_]; \
  aR0 = __builtin_amdgcn_mfma_f32_16x16x32_bf16(a0_, w0_, aR0, 0,0,0); \
  aR1 = __builtin_amdgcn_mfma_f32_16x16x32_bf16(a1_, w0_, aR1, 0,0,0); \
  aZ0 = __builtin_amdgcn_mfma_f32_16x16x32_bf16(a0_, w1_, aZ0, 0,0,0); \
  aZ1 = __builtin_amdgcn_mfma_f32_16x16x32_bf16(a1_, w1_, aZ1, 0,0,0); \
  G2A = __builtin_amdgcn_mfma_f32_16x16x32_bf16(a0_, w2_, G2A, 0,0,0); \
  G2B = __builtin_amdgcn_mfma_f32_16x16x32_bf16(a1_, w2_, G2B, 0,0,0); }

#define LDH(C, M)     (*(const uint4*)(hs + (size_t)rb*32768 + (size_t)(C)*1024 + (M)*512 + la*32 + lb*8))
#define LDX(TT, S, M) (*(const uint4*)(xsrc + (size_t)(TT)*xstride + (size_t)rb*4096 + (size_t)(S)*1024 + (M)*512 + la*32 + lb*8))

__global__ __launch_bounds__(128) void gru_wave(
    const bf16* __restrict__ xsrc, int xstride, int nsteps, int coop,
    const bf16* __restrict__ Wpk, const float* __restrict__ bcat,
    const float* __restrict__ hin_plain, float* __restrict__ hout_plain,
    bf16* __restrict__ hbplain,
    bf16* __restrict__ hpk0, bf16* __restrict__ hpk1,
    unsigned* __restrict__ prog)
{
  __shared__ bf16 Wl[3*36*512];       // 108 KB
  const int tid = threadIdx.x, wv = tid >> 6, lane = tid & 63;
  const int ub = blockIdx.x & 63, q = blockIdx.x >> 6;
  const int u0 = ub*16;

  {  // weights -> LDS once
    const bf16* wsrc = Wpk + (size_t)ub*(3*36*512);
    #pragma unroll
    for (int i = 0; i < 54; ++i){
      int c = i*128 + tid;
      GLD16(&Wl[c*8], wsrc + (size_t)c*8);
    }
  }

  const int la = lane & 15, lb = lane >> 4;
  const int r0 = q*64 + wv*32;
  const int rb = r0 >> 5;
  const int ucol = u0 + la;
  const float bR = bcat[ucol], bZ = bcat[1024+ucol], bI = bcat[2048+ucol], bN = bcat[3072+ucol];

  uint4 qa[12], qb[12];
  #pragma unroll
  for (int s = 0; s < 4; ++s){ qa[s] = LDX(0,s,0); qb[s] = LDX(0,s,1); }

  VMWAIT(0); BARRIER();   // weights (and first x) resident

  float hr[2][4];
  if (nsteps == 1){
    #pragma unroll
    for (int m = 0; m < 2; ++m)
      #pragma unroll
      for (int r = 0; r < 4; ++r)
        hr[m][r] = hin_plain[(size_t)(r0 + m*16 + lb*4 + r)*1024 + ucol];
  } else {
    #pragma unroll
    for (int m = 0; m < 2; ++m)
      #pragma unroll
      for (int r = 0; r < 4; ++r) hr[m][r] = 0.f;
  }

  for (int t = 0; t < nsteps; ++t){
    if (coop && t > 0){
      unsigned v = __hip_atomic_load(&prog[q*64 + lane], __ATOMIC_ACQUIRE, __HIP_MEMORY_SCOPE_AGENT);
      while (__ballot(v >= (unsigned)t) != ~0ULL){
        __builtin_amdgcn_s_sleep(8);
        v = __hip_atomic_load(&prog[q*64 + lane], __ATOMIC_ACQUIRE, __HIP_MEMORY_SCOPE_AGENT);
      }
      __builtin_amdgcn_sched_barrier(0);
    }
    const bf16* hs = (t & 1) ? hpk1 : hpk0;
    #pragma unroll
    for (int c = 0; c < 8; ++c){ qa[4+c] = LDH(c,0); qb[4+c] = LDH(c,1); }

    f32x4 z4 = {0.f,0.f,0.f,0.f};
    f32x4 aR0=z4, aR1=z4, aZ0=z4, aZ1=z4, aI0=z4, aI1=z4, aN0=z4, aN1=z4;

    #pragma unroll
    for (int j = 0; j < 4; ++j){               // x slices (gate2 = I)
      SLC2(qa[j], qb[j], j, aI0, aI1);
      qa[j] = LDH(j+8,0); qb[j] = LDH(j+8,1);  // slice j+12 = h chunk j+8
    }
    #pragma unroll
    for (int i = 0; i < 32; ++i){              // h slices (gate2 = N)
      const int sl = (i+4)%12;
      SLC2(qa[sl], qb[sl], 4+i, aN0, aN1);
      if (i <= 19){      qa[sl] = LDH(i+12,0);      qb[sl] = LDH(i+12,1); }
      else if (i <= 23){ qa[sl] = LDX(t+1,i-20,0);  qb[sl] = LDX(t+1,i-20,1); }
    }

    bf16* hd = (t & 1) ? hpk0 : hpk1;
    const bool last = (t == nsteps-1);
    const size_t pwb = (size_t)rb*32768 + (size_t)(ub>>1)*1024 + (u0 & 16) + la;
    #pragma unroll
    for (int m = 0; m < 2; ++m){
      f32x4 vR = m ? aR1 : aR0;
      f32x4 vZ = m ? aZ1 : aZ0;
      f32x4 vI = m ? aI1 : aI0;
      f32x4 vN = m ? aN1 : aN0;
      #pragma unroll
      for (int r = 0; r < 4; ++r){
        float rg = 1.f/(1.f + __expf(-(vR[r] + bR)));
        float zg = 1.f/(1.f + __expf(-(vZ[r] + bZ)));
        float ng = tanhf((vI[r] + bI) + rg*(vN[r] + bN));
        float hv = (1.f - zg)*ng + zg*hr[m][r];
        hr[m][r] = hv;
        hd[pwb + m*512 + (lb*4 + r)*32] = __float2bfloat16(hv);
        if (last){
          int row = r0 + m*16 + lb*4 + r;
          hout_plain[(size_t)row*1024 + ucol] = hv;
          if (hbplain) hbplain[(size_t)row*1024 + ucol] = __float2bfloat16(hv);
        }
      }
    }
    if (coop){
      __syncthreads();
      if (tid == 0){
        __threadfence();
        __hip_atomic_store(&prog[q*64 + ub], (unsigned)(t+1), __ATOMIC_RELEASE, __HIP_MEMORY_SCOPE_AGENT);
      }
    }
  }
}

// ---------------- pipelined generic GEMM: C[M,N] = A @ B^T (+bias/epilogue) ----------------
__global__ __launch_bounds__(256) void gemm64(
    const bf16* __restrict__ Am, const bf16* __restrict__ Bm, int K,
    const float* __restrict__ bias, const float* __restrict__ addmat,
    float* __restrict__ C, bf16* __restrict__ Cbf, int N, int MODE)
{
  __shared__ bf16 As[3][64*64];
  __shared__ bf16 Bs[3][64*64];
  const int tid = threadIdx.x;
  const int wave = tid >> 6, lane = tid & 63;
  const int m0 = blockIdx.x*64, n0 = blockIdx.y*64;
  const int fr = lane & 31, kh = lane >> 5;
  const int wm = (wave >> 1)*32, wn = (wave & 1)*32;
  const int KT = K >> 6;

  f32x16 acc = {0.f,0.f,0.f,0.f,0.f,0.f,0.f,0.f,0.f,0.f,0.f,0.f,0.f,0.f,0.f,0.f};

  auto STAGE = [&](int buf, int kt){
    #pragma unroll
    for (int q = 0; q < 2; ++q){
      int idx = q*256 + tid;
      int row = idx >> 3, cp = idx & 7, csw = cp ^ (row & 7);
      GLD16(&As[buf][idx*8], Am + (size_t)(m0+row)*K + kt*64 + csw*8);
    }
    #pragma unroll
    for (int q = 0; q < 2; ++q){
      int idx = q*256 + tid;
      int row = idx >> 3, cp = idx & 7, csw = cp ^ (row & 7);
      GLD16(&Bs[buf][idx*8], Bm + (size_t)(n0+row)*K + kt*64 + csw*8);
    }
  };
  auto COMPUTE = [&](int buf){
    const bf16* Ab = &As[buf][0];
    const bf16* Bb = &Bs[buf][0];
    #pragma unroll
    for (int ks = 0; ks < 4; ++ks){
      int ca = ks*2 + kh;
      v8bf av = *(const v8bf*)&Ab[(wm+fr)*64 + ((ca ^ ((wm+fr)&7))*8)];
      v8bf bv = *(const v8bf*)&Bb[(wn+fr)*64 + ((ca ^ ((wn+fr)&7))*8)];
      acc = __builtin_amdgcn_mfma_f32_32x32x16_bf16(av, bv, acc, 0, 0, 0);
    }
  };

  STAGE(0, 0);
  if (KT > 1){ STAGE(1, 1); VMWAIT(4); } else { VMWAIT(0); }
  BARRIER();
  for (int kt = 0; kt < KT; ++kt){
    if (kt + 2 < KT) STAGE((kt+2)%3, kt+2);
    COMPUTE(kt%3);
    if (kt + 2 < KT){ VMWAIT(4); BARRIER(); }
    else if (kt + 1 < KT){ VMWAIT(0); BARRIER(); }
  }

  const int col = n0 + wn + fr;
  float bb = bias ? bias[col] : 0.f;
  #pragma unroll
  for (int r = 0; r < 16; ++r){
    int row = m0 + wm + (r&3) + 8*(r>>2) + 4*kh;
    float v = acc[r] + bb;
    if (MODE == 1) v = fmaxf(v, 0.f) + addmat[(size_t)row*N + col];
    if (C)   C[(size_t)row*N + col] = v;
    if (Cbf) Cbf[(size_t)row*N + col] = __float2bfloat16(v);
  }
}

// ---------------- attention: one block per (b,h) ----------------
__global__ __launch_bounds__(256) void k_attn(const bf16* __restrict__ qkv,
                                              bf16* __restrict__ ctxbf){
  __shared__ char smem[65536];
  bf16* qs = (bf16*)smem;               // [64][256] swizzled
  bf16* ks = qs + 64*256;
  float* sc = (float*)smem;             // [64][65], reuse
  float* cs = (float*)(smem + 32768);
  const int h = blockIdx.x, b = blockIdx.y;
  const int tid = threadIdx.x, wave = tid >> 6, lane = tid & 63;
  const int fr = lane & 31, kh = lane >> 5;
  const int wm = (wave >> 1)*32, wn = (wave & 1)*32;

  #pragma unroll
  for (int i = 0; i < 8; ++i){
    int idx = i*256 + tid;
    int row = idx >> 5, cp = idx & 31, csw = cp ^ (row & 7);
    GLD16(&qs[idx*8], qkv + (size_t)(b*F_ + row)*3072 + h*DH_ + csw*8);
  }
  #pragma unroll
  for (int i = 0; i < 8; ++i){
    int idx = i*256 + tid;
    int row = idx >> 5, cp = idx & 31, csw = cp ^ (row & 7);
    GLD16(&ks[idx*8], qkv + (size_t)(b*F_ + row)*3072 + H_ + h*DH_ + csw*8);
  }
  __syncthreads();

  f32x16 acc = {0.f,0.f,0.f,0.f,0.f,0.f,0.f,0.f,0.f,0.f,0.f,0.f,0.f,0.f,0.f,0.f};
  #pragma unroll
  for (int i = 0; i < 16; ++i){
    int ca = i*2 + kh;
    v8bf av = *(const v8bf*)&qs[((wm+fr)*32 + (ca ^ ((wm+fr)&7)))*8];
    v8bf bv = *(const v8bf*)&ks[((wn+fr)*32 + (ca ^ ((wn+fr)&7)))*8];
    acc = __builtin_amdgcn_mfma_f32_32x32x16_bf16(av, bv, acc, 0, 0, 0);
  }
  __syncthreads();
  #pragma unroll
  for (int r = 0; r < 16; ++r){
    int row = wm + (r&3) + 8*(r>>2) + 4*kh;
    sc[row*65 + (wn+fr)] = acc[r]*0.0625f;
  }
  __syncthreads();
  if (tid < F_){
    float m = -1e30f;
    for (int k2 = 0; k2 < F_; ++k2) m = fmaxf(m, sc[tid*65+k2]);
    float s = 0.f;
    for (int k2 = 0; k2 < F_; ++k2){ float e = __expf(sc[tid*65+k2]-m); sc[tid*65+k2] = e; s += e; }
    float is = 1.f/s;
    for (int k2 = 0; k2 < F_; ++k2) sc[tid*65+k2] *= is;
  }
  __syncthreads();
  if (tid < F_){
    float s = 0.f;
    for (int r = 0; r < F_; ++r) s += sc[r*65+tid];
    cs[tid] = s;
  }
  __syncthreads();
  float a = 0.f;
  for (int k2 = 0; k2 < F_; ++k2){
    float v = __bfloat162float(qkv[(size_t)(b*F_+k2)*3072 + 2*H_ + h*DH_ + tid]);
    a += cs[k2]*v;
  }
  ctxbf[(size_t)b*H_ + h*DH_ + tid] = __float2bfloat16(a * (1.f/61.f));
}

// ---------------- SPL: parent chains + W2 head + x update ----------------
__constant__ int LVJ[14] = {0,1,6,8,9, 2,3,7,10,11, 4,5,12,13};
__constant__ int LVO[4]  = {0,5,10,14};
__constant__ int PAR_[14] = {-1,-1,0,1,2,3,-1,6,-1,-1,8,9,10,11};

__global__ __launch_bounds__(128) void spl_all(const float* __restrict__ hh_pre, const float* __restrict__ W1,
                        const float* __restrict__ W2, const float* __restrict__ b2,
                        float* __restrict__ x, bf16* __restrict__ xpk,
                        float* __restrict__ out, int tstep){
  __shared__ float preds_s[4][128];
  __shared__ float hh_s[128][5];
  int b0 = blockIdx.x*4, t = threadIdx.x;   // grid 64, block 128
  for (int L = 0; L < 3; ++L){
    for (int ji = LVO[L]; ji < LVO[L+1]; ++ji){
      int j = LVJ[ji], p = PAR_[j];
      float acc[4];
      #pragma unroll
      for (int bb = 0; bb < 4; ++bb) acc[bb] = hh_pre[(size_t)(b0+bb)*1792 + j*128 + t];
      if (p >= 0){
        #pragma unroll
        for (int ii = 0; ii < 9; ++ii){
          float w = W1[(size_t)(j*128 + t)*1033 + 1024 + ii];
          #pragma unroll
          for (int bb = 0; bb < 4; ++bb) acc[bb] += w * preds_s[bb][p*9 + ii];
        }
      }
      #pragma unroll
      for (int bb = 0; bb < 4; ++bb) hh_s[t][bb] = fmaxf(acc[bb], 0.f);
      __syncthreads();
      if (t < 72){
        int pp = t >> 1, half = t & 1;
        int bb = pp/9, oi = pp%9;
        const float* w2r = W2 + (size_t)(j*9 + oi)*128 + half*64;
        float s = 0.f;
        #pragma unroll
        for (int tt = 0; tt < 64; ++tt) s += hh_s[half*64 + tt][bb] * w2r[tt];
        s += __shfl_xor(s, 1);
        if (half == 0) preds_s[bb][j*9 + oi] = tanhf(s + b2[j*9 + oi]);
      }
      __syncthreads();
    }
  }
  for (int i = t; i < 4*D_; i += 128){
    int bb = i / D_, d = i % D_;
    int row = b0 + bb;
    size_t xi = (size_t)row*D_ + d;
    float v = x[xi] + preds_s[bb][d];
    x[xi] = v;
    xpk[((row>>5)*4 + (d>>5))*1024 + (row&31)*32 + (d&31)] = __float2bfloat16(v);
    out[((size_t)row*PRED_ + tstep)*D_ + d] = v;
  }
}

// ---------------- launch ----------------
extern "C" void kernel_launch(void* const* d_in, const int* in_sizes, int n_in,
                              void* d_out, int out_size, void* d_ws, size_t ws_size,
                              hipStream_t stream){
  (void)in_sizes; (void)n_in; (void)out_size; (void)ws_size;
  const float* poses = (const float*)d_in[0];
  const float* gWih  = (const float*)d_in[1];
  const float* gWhh  = (const float*)d_in[2];
  const float* gbih  = (const float*)d_in[3];
  const float* gbhh  = (const float*)d_in[4];
  const float* preW  = (const float*)d_in[5];
  const float* preb  = (const float*)d_in[6];
  const float* fpW   = (const float*)d_in[7];
  const float* fpb   = (const float*)d_in[8];
  const float* inW   = (const float*)d_in[9];
  const float* inb   = (const float*)d_in[10];
  const float* outW  = (const float*)d_in[11];
  const float* outb  = (const float*)d_in[12];
  const float* sW1   = (const float*)d_in[13];
  const float* sb1   = (const float*)d_in[14];
  const float* sW2   = (const float*)d_in[15];
  const float* sb2   = (const float*)d_in[16];
  float* out = (float*)d_out;

  char* w = (char*)d_ws;
  size_t off = 0;
  auto alloc = [&](size_t bytes)->char*{ char* p = w + off; off += (bytes + 255) & ~(size_t)255; return p; };
  float* cosT   = (float*)alloc(7320*4);
  float* bc     = (float*)alloc(3072*4);
  float* motion = (float*)alloc((size_t)256*1024*4);
  float* hA     = (float*)alloc((size_t)256*1024*4);
  float* hB     = (float*)alloc((size_t)256*1024*4);
  float* xcur   = (float*)alloc((size_t)256*126*4);
  float* hhpre  = (float*)alloc((size_t)256*1792*4);
  float* bcat   = (float*)alloc(4096*4);
  unsigned* prog= (unsigned*)alloc(1024);
  bf16* posespk = (bf16*)alloc((size_t)121*32768*2);   // +1 step pad for cross-barrier prefetch
  bf16* Wcat    = (bf16*)alloc((size_t)4096*1152*2);
  bf16* Wpk     = (bf16*)alloc((size_t)64*108*512*2);
  bf16* prebf   = (bf16*)alloc((size_t)1024*1024*2);
  bf16* outbf   = (bf16*)alloc((size_t)1024*1024*2);
  bf16* inbf    = (bf16*)alloc((size_t)3072*1024*2);
  bf16* fpwt    = (bf16*)alloc((size_t)128*1024*2);
  bf16* w1h     = (bf16*)alloc((size_t)1792*1024*2);
  bf16* ctxbf   = (bf16*)alloc((size_t)256*1024*2);
  bf16* hpkA    = (bf16*)alloc((size_t)256*1024*2);
  bf16* hpkB    = (bf16*)alloc((size_t)256*1024*2);
  bf16* hbplain = (bf16*)alloc((size_t)256*1024*2);
  bf16* xpk     = (bf16*)alloc((size_t)32768*2);
  bf16* hidbf   = (bf16*)alloc((size_t)256*1024*2);
  bf16* Wcbf    = (bf16*)alloc((size_t)3072*128*2);
  bf16* freqbf  = (bf16*)alloc((size_t)B_*F_*128*2);
  bf16* qkvbf   = (bf16*)alloc((size_t)15680*3072*2);

  hipMemsetAsync(hpkA, 0, (size_t)256*1024*2, stream);
  hipMemsetAsync(prog, 0, 1024, stream);

  k_cos<<<29, 256, 0, stream>>>(cosT);
  k_dft2<<<B_, 256, 0, stream>>>(poses, cosT, freqbf);
  c_poses<<<dim3(SEED_, B_), 128, 0, stream>>>(poses, posespk);
  c_xinit<<<B_, 128, 0, stream>>>(poses, xcur, xpk);
  c_wcat<<<4096, 256, 0, stream>>>(gWih, gWhh, Wcat);
  c_bcat<<<16, 256, 0, stream>>>(gbih, gbhh, bcat);
  c_wpk<<<1728, 256, 0, stream>>>(Wcat, Wpk);
  c_bf<<<4096, 256, 0, stream>>>(preW, prebf, 1024*1024);
  c_bf<<<4096, 256, 0, stream>>>(outW, outbf, 1024*1024);
  c_bf<<<12288, 256, 0, stream>>>(inW, inbf, 3072*1024);
  c_fpwt<<<128, 256, 0, stream>>>(fpW, fpwt);
  c_w1hid<<<7168, 256, 0, stream>>>(sW1, w1h);
  k_bc<<<768, 256, 0, stream>>>(inW, inb, fpb, bc);

  // Wc = inproj @ fp_W  (3072 x 128, bf16)
  gemm64<<<dim3(48, 2), 256, 0, stream>>>(inbf, fpwt, 1024, nullptr, nullptr, nullptr, Wcbf, 128, 0);
  // qkv = freq @ Wc^T + bc  (15616 x 3072, bf16)
  gemm64<<<dim3(244, 48), 256, 0, stream>>>(freqbf, Wcbf, 128, bc, nullptr, nullptr, qkvbf, 3072, 0);
  k_attn<<<dim3(HEADS_, B_), 256, 0, stream>>>(qkvbf, ctxbf);
  // motion_ctx = ctx_mean @ outproj^T + outb
  gemm64<<<dim3(4, 16), 256, 0, stream>>>(ctxbf, outbf, 1024, outb, nullptr, motion, nullptr, 1024, 0);

  // encoder: cooperative, 120 steps, flag-synced; final h -> hA (fp32) + hpkA (packed, t=119 odd)
  {
    const bf16* a0 = posespk; int a1 = 32768; int a2 = SEED_; int a3 = 1;
    const bf16* a4 = Wpk; const float* a5 = bcat;
    const float* a6 = hA; float* a7 = hA; bf16* a8 = nullptr;
    bf16* a9 = hpkA; bf16* a10 = hpkB; unsigned* a11 = prog;
    void* args[] = { &a0, &a1, &a2, &a3, &a4, &a5, &a6, &a7, &a8, &a9, &a10, &a11 };
    hipLaunchCooperativeKernel(reinterpret_cast<void*>(gru_wave), dim3(256), dim3(128),
                               args, 0, stream);
  }

  float* hc = hA;  float* hn = hB;
  bf16* hpc = hpkA; bf16* hpn = hpkB;

  // decoder: 24 steps
  for (int t = 0; t < PRED_; ++t){
    gru_wave<<<256, 128, 0, stream>>>(xpk, 0, 1, 0, Wpk, bcat, hc, hn, hbplain, hpc, hpn, nullptr);
    { float* tf = hc; hc = hn; hn = tf; bf16* tb = hpc; hpc = hpn; hpn = tb; }
    gemm64<<<dim3(4, 16), 256, 0, stream>>>(hbplain, prebf, 1024, preb, motion, nullptr, hidbf, 1024, 1);
    gemm64<<<dim3(4, 28), 256, 0, stream>>>(hidbf, w1h, 1024, sb1, nullptr, hhpre, nullptr, 1792, 0);
    spl_all<<<64, 128, 0, stream>>>(hhpre, sW1, sW2, sb2, xcur, xpk, out, t);
  }
}

// Round 9
// 4340.886 us; speedup vs baseline: 1.3433x; 1.3433x over previous
//
#include <hip/hip_runtime.h>
#include <hip/hip_bf16.h>

typedef __hip_bfloat16 bf16;
typedef __attribute__((ext_vector_type(8))) short v8bf;     // 8 bf16 (4 VGPR)
typedef __attribute__((ext_vector_type(16))) float f32x16;
typedef __attribute__((ext_vector_type(4))) float f32x4;

#define B_    256
#define SEED_ 120
#define PRED_ 24
#define D_    126
#define H_    1024
#define F_    61
#define HEADS_ 4
#define DH_   256

#define GLD16(lds, g) __builtin_amdgcn_global_load_lds( \
    (const __attribute__((address_space(1))) unsigned int*)(g), \
    (__attribute__((address_space(3))) unsigned int*)(lds), 16, 0, 0)
#define VMWAIT(n) asm volatile("s_waitcnt vmcnt(" #n ")" ::: "memory")
#define BARRIER() do { __builtin_amdgcn_s_barrier(); __builtin_amdgcn_sched_barrier(0); } while(0)

__device__ inline v8bf u2v(uint4 x){ union { uint4 u; v8bf v; } c; c.u = x; return c.v; }

// ---------------- small precompute kernels ----------------
__global__ void k_cos(float* cosT){
  int i = blockIdx.x*256 + threadIdx.x;
  if (i < F_*SEED_){
    int f = i / SEED_, t = i % SEED_;
    int ph = (f*t) % SEED_;
    cosT[i] = cosf(6.283185307179586f * (float)ph / (float)SEED_);
  }
}

// one block per b; poses row staged once in LDS; 31 f-accumulators per thread.
__global__ __launch_bounds__(256) void k_dft2(const float* __restrict__ poses,
                      const float* __restrict__ cosT, bf16* __restrict__ freqbf){
  __shared__ float pl[SEED_*128];      // 60 KB
  int b = blockIdx.x, tid = threadIdx.x;
  for (int i = tid; i < SEED_*D_; i += 256){
    int t = i / D_, d = i - t*D_;
    pl[t*128 + d] = poses[((size_t)b*(SEED_+PRED_) + t)*D_ + d];
  }
  __syncthreads();
  int d = tid & 127, f0 = tid >> 7;    // f = f0 + 2j
  float acc[31];
  #pragma unroll
  for (int j = 0; j < 31; ++j) acc[j] = 0.f;
  for (int t = 0; t < SEED_; ++t){
    float v = pl[t*128 + d];
    #pragma unroll
    for (int j = 0; j < 31; ++j){
      int f = f0 + j*2;
      if (f < F_) acc[j] += cosT[f*SEED_ + t] * v;
    }
  }
  #pragma unroll
  for (int j = 0; j < 31; ++j){
    int f = f0 + j*2;
    if (f < F_) freqbf[((size_t)b*F_ + f)*128 + d] = __float2bfloat16(d < D_ ? acc[j] : 0.f);
  }
}

// pack poses into per-step 32x32 tiles: pk[t][ (b>>5)*4 + (c>>5) ][ (b&31)*32 + (c&31) ]
__global__ void c_poses(const float* __restrict__ poses, bf16* __restrict__ pk){
  int t = blockIdx.x, b = blockIdx.y, c = threadIdx.x;  // block 128
  float v = (c < D_) ? poses[((size_t)b*(SEED_+PRED_) + t)*D_ + c] : 0.f;
  pk[(size_t)t*32768 + ((b>>5)*4 + (c>>5))*1024 + (b&31)*32 + (c&31)] = __float2bfloat16(v);
}

__global__ void c_xinit(const float* __restrict__ poses, float* __restrict__ x, bf16* __restrict__ xpk){
  int b = blockIdx.x, c = threadIdx.x;  // block 128
  float v = (c < D_) ? poses[((size_t)b*(SEED_+PRED_) + (SEED_-1))*D_ + c] : 0.f;
  if (c < D_) x[b*D_ + c] = v;
  xpk[((b>>5)*4 + (c>>5))*1024 + (b&31)*32 + (c&31)] = __float2bfloat16(v);
}

__global__ void c_bf(const float* __restrict__ s, bf16* __restrict__ d, int n){
  int i = blockIdx.x*256 + threadIdx.x;
  if (i < n) d[i] = __float2bfloat16(s[i]);
}

__global__ void c_fpwt(const float* __restrict__ fpW, bf16* __restrict__ o){
  int dd = blockIdx.x;                       // 0..127
  for (int k = threadIdx.x; k < H_; k += 256)
    o[(size_t)dd*H_ + k] = __float2bfloat16(dd < D_ ? fpW[(size_t)k*D_ + dd] : 0.f);
}

__global__ void c_w1hid(const float* __restrict__ W1, bf16* __restrict__ o){
  int i = blockIdx.x*256 + threadIdx.x;      // 1792*1024
  if (i < 1792*1024){ int r = i >> 10, c = i & 1023; o[i] = __float2bfloat16(W1[(size_t)r*1033 + c]); }
}

// combined GRU weight: rows 0..1023=[Wih_r|Whh_r]; 1024..2047=[Wih_z|Whh_z];
// 2048..3071=[Wih_n|0]; 3072..4095=[0|Whh_n]  (row width 1152 = 128 x | 1024 h)
__global__ void c_wcat(const float* __restrict__ Wih, const float* __restrict__ Whh, bf16* __restrict__ o){
  int r = blockIdx.x;
  int jr; bool hasx, hash;
  if (r < 2048){ jr = r; hasx = true; hash = true; }
  else if (r < 3072){ jr = r; hasx = true; hash = false; }
  else { jr = r - 1024; hasx = false; hash = true; }
  bf16* row = o + (size_t)r*1152;
  for (int c = threadIdx.x; c < 1152; c += 256){
    float v = 0.f;
    if (c < D_) { if (hasx) v = Wih[(size_t)jr*D_ + c]; }
    else if (c >= 128){ if (hash) v = Whh[(size_t)jr*H_ + (c-128)]; }
    row[c] = __float2bfloat16(v);
  }
}

__global__ void c_bcat(const float* __restrict__ bih, const float* __restrict__ bhh, float* __restrict__ o){
  int r = blockIdx.x*256 + threadIdx.x;
  if (r >= 4096) return;
  float v;
  if (r < 2048) v = bih[r] + bhh[r];
  else if (r < 3072) v = bih[r];
  else v = bhh[r - 1024];
  o[r] = v;
}

// pack GRU weights into MFMA B-fragment order:
// chunk = ((ub*3+g)*36+ks): elem[l*8+e] = W_g[ub*16+(l&15)][ks*32+(l>>4)*8+e]
__global__ __launch_bounds__(256) void c_wpk(const bf16* __restrict__ Wcat, bf16* __restrict__ Wpk){
  int chunk = blockIdx.x*4 + (threadIdx.x >> 6);
  int l = threadIdx.x & 63;
  int ks = chunk % 36; int t2 = chunk / 36; int g = t2 % 3; int ub = t2 / 3;
  int unit = ub*16 + (l & 15);
  bf16* dst = Wpk + (size_t)chunk*512 + l*8;
  #pragma unroll
  for (int e = 0; e < 8; ++e){
    int k = ks*32 + (l>>4)*8 + e;
    int row = (g==0) ? unit : (g==1) ? (1024+unit) : (k < 128 ? 2048+unit : 3072+unit);
    dst[e] = Wcat[(size_t)row*1152 + k];
  }
}

// bc = inproj @ fp_b + in_b : wave-per-row float4 reduction. grid 768, block 256.
__global__ __launch_bounds__(256) void k_bc(const float* __restrict__ inW, const float* __restrict__ inb,
                     const float* __restrict__ fpb, float* __restrict__ bc){
  int wave = threadIdx.x >> 6, lane = threadIdx.x & 63;
  int r = blockIdx.x*4 + wave;
  const float4* row = (const float4*)(inW + (size_t)r*H_);
  const float4* fp4 = (const float4*)fpb;
  float s = 0.f;
  #pragma unroll
  for (int i = 0; i < 4; ++i){
    float4 a = row[lane + i*64];
    float4 b = fp4[lane + i*64];
    s += a.x*b.x + a.y*b.y + a.z*b.z + a.w*b.w;
  }
  #pragma unroll
  for (int off = 32; off; off >>= 1) s += __shfl_down(s, off);
  if (lane == 0) bc[r] = s + inb[r];
}

// ---------------- wave-autonomous GRU, packed-tile A operands, flag sync ----------------
// grid 128 = 64 unit-slices x 2 batch-halves; block 512 (8 waves x 16 rows).
// Weights LDS-resident (108KB). A loads: contiguous 1KB per wave from 32x32 tiles.
// Ring of 12 named uint4 (depth 12 divides 36 -> phase-invariant across steps).
// Encoder sync: per-block monotonic flag prog[bs*64+ub]. Producer: vmcnt(0) ->
// syncthreads -> tid0 {fence(release,agent) [one L2-wb] + relaxed agent flag store}.
// Consumer: wave0 polls its half's 64 flags with RELAXED agent loads (sc1, no inv;
// every 64th poll acquire as hang-insurance), then ONE fence(acquire,agent)/block.
// 2-buffer ping-pong is race-free: producers of a block's rows == its readers.
#define SLC(QQ, KS, GACC) { \
  v8bf a_ = u2v(QQ); \
  v8bf w0_ = *(const v8bf*)&Wl[(0*36+(KS))*512 + lane*8]; \
  v8bf w1_ = *(const v8bf*)&Wl[(1*36+(KS))*512 + lane*8]; \
  v8bf w2_ = *(const v8bf*)&Wl[(2*36+(KS))*512 + lane*8]; \
  aR = __builtin_amdgcn_mfma_f32_16x16x32_bf16(a_, w0_, aR, 0,0,0); \
  aZ = __builtin_amdgcn_mfma_f32_16x16x32_bf16(a_, w1_, aZ, 0,0,0); \
  GACC = __builtin_amdgcn_mfma_f32_16x16x32_bf16(a_, w2_, GACC, 0,0,0); }

#define LDH(C)    (*(const uint4*)(hs + hbase + (size_t)(C)*1024))
#define LDXT(TT,C)(*(const uint4*)(xpk + (size_t)(TT)*xstride + xbase + (size_t)(C)*1024))

__global__ __launch_bounds__(512) void gru_wave(
    const bf16* __restrict__ xpk, int xstride, int nsteps, int coop,
    const bf16* __restrict__ Wpk, const float* __restrict__ bcat,
    const float* __restrict__ hin_plain, float* __restrict__ hout_plain,
    bf16* __restrict__ hbplain,
    bf16* __restrict__ hpk0, bf16* __restrict__ hpk1,
    unsigned* __restrict__ prog)
{
  __shared__ bf16 Wl[3*36*512];       // 108 KB
  const int tid = threadIdx.x, wave = tid >> 6, lane = tid & 63;
  const int ub = blockIdx.x >> 1, bs = blockIdx.x & 1;
  const int u0 = ub*16;

  {  // weights -> LDS once
    const bf16* wsrc = Wpk + (size_t)ub*(3*36*512);
    #pragma unroll
    for (int i = 0; i < 14; ++i){
      int c = i*512 + tid;
      if (c < 6912) GLD16(&Wl[c*8], wsrc + (size_t)c*8);
    }
  }
  VMWAIT(0); BARRIER();

  const int la = lane & 15, lb = lane >> 4;
  const int r0 = bs*128 + wave*16;
  const int rb = r0 >> 5, y = wave & 1;
  const int ucol = u0 + la;
  const float bR = bcat[ucol], bZ = bcat[1024+ucol], bI = bcat[2048+ucol], bN = bcat[3072+ucol];
  const size_t hbase = (size_t)rb*32768 + (size_t)y*512 + la*32 + lb*8;
  const size_t xbase = (size_t)rb*4096  + (size_t)y*512 + la*32 + lb*8;
  // packed write base: tile (rb, u0>>5), row-in-tile = y*16 + lb*4 + rr, col-in-tile = (u0&16)+la
  const size_t pwb = (size_t)rb*32768 + (size_t)(u0>>5)*1024 + (size_t)y*512 + (u0&16) + la;

  float hr[4];
  if (nsteps == 1){
    #pragma unroll
    for (int r = 0; r < 4; ++r) hr[r] = hin_plain[(size_t)(r0 + lb*4 + r)*1024 + ucol];
  } else {
    #pragma unroll
    for (int r = 0; r < 4; ++r) hr[r] = 0.f;
  }

  uint4 q0 = LDXT(0,0), q1 = LDXT(0,1), q2 = LDXT(0,2), q3 = LDXT(0,3);
  uint4 q4, q5, q6, q7, q8, q9, q10, q11;

  for (int t = 0; t < nsteps; ++t){
    if (coop && t > 0){
      if (wave == 0){
        unsigned v = __hip_atomic_load(&prog[bs*64 + lane], __ATOMIC_RELAXED, __HIP_MEMORY_SCOPE_AGENT);
        int spins = 0;
        while (__ballot(v >= (unsigned)t) != ~0ULL){
          __builtin_amdgcn_s_sleep(4);
          if ((++spins & 63) == 0)
            v = __hip_atomic_load(&prog[bs*64 + lane], __ATOMIC_ACQUIRE, __HIP_MEMORY_SCOPE_AGENT);
          else
            v = __hip_atomic_load(&prog[bs*64 + lane], __ATOMIC_RELAXED, __HIP_MEMORY_SCOPE_AGENT);
        }
      }
      __syncthreads();
      __builtin_amdgcn_fence(__ATOMIC_ACQUIRE, "agent");   // one L2-inv per block per step
      __builtin_amdgcn_sched_barrier(0);
    }
    const bf16* hs = (t & 1) ? hpk1 : hpk0;
    q4 = LDH(0); q5 = LDH(1); q6 = LDH(2); q7 = LDH(3);
    q8 = LDH(4); q9 = LDH(5); q10 = LDH(6); q11 = LDH(7);

    f32x4 z4 = {0.f,0.f,0.f,0.f};
    f32x4 aR = z4, aZ = z4, aI = z4, aN = z4;

    SLC(q0,0,aI)  q0 = LDH(8);
    SLC(q1,1,aI)  q1 = LDH(9);
    SLC(q2,2,aI)  q2 = LDH(10);
    SLC(q3,3,aI)  q3 = LDH(11);
    SLC(q4,4,aN)  q4 = LDH(12);
    SLC(q5,5,aN)  q5 = LDH(13);
    SLC(q6,6,aN)  q6 = LDH(14);
    SLC(q7,7,aN)  q7 = LDH(15);
    SLC(q8,8,aN)  q8 = LDH(16);
    SLC(q9,9,aN)  q9 = LDH(17);
    SLC(q10,10,aN) q10 = LDH(18);
    SLC(q11,11,aN) q11 = LDH(19);
    SLC(q0,12,aN) q0 = LDH(20);
    SLC(q1,13,aN) q1 = LDH(21);
    SLC(q2,14,aN) q2 = LDH(22);
    SLC(q3,15,aN) q3 = LDH(23);
    SLC(q4,16,aN) q4 = LDH(24);
    SLC(q5,17,aN) q5 = LDH(25);
    SLC(q6,18,aN) q6 = LDH(26);
    SLC(q7,19,aN) q7 = LDH(27);
    SLC(q8,20,aN) q8 = LDH(28);
    SLC(q9,21,aN) q9 = LDH(29);
    SLC(q10,22,aN) q10 = LDH(30);
    SLC(q11,23,aN) q11 = LDH(31);
    SLC(q0,24,aN) q0 = LDXT(t+1,0);
    SLC(q1,25,aN) q1 = LDXT(t+1,1);
    SLC(q2,26,aN) q2 = LDXT(t+1,2);
    SLC(q3,27,aN) q3 = LDXT(t+1,3);
    SLC(q4,28,aN)
    SLC(q5,29,aN)
    SLC(q6,30,aN)
    SLC(q7,31,aN)
    SLC(q8,32,aN)
    SLC(q9,33,aN)
    SLC(q10,34,aN)
    SLC(q11,35,aN)

    bf16* hd = (t & 1) ? hpk0 : hpk1;
    const bool last = (t == nsteps-1);
    #pragma unroll
    for (int r = 0; r < 4; ++r){
      float rg = 1.f/(1.f + __expf(-(aR[r] + bR)));
      float zg = 1.f/(1.f + __expf(-(aZ[r] + bZ)));
      float ng = tanhf((aI[r] + bI) + rg*(aN[r] + bN));
      float hv = (1.f - zg)*ng + zg*hr[r];
      hr[r] = hv;
      hd[pwb + (size_t)(lb*4 + r)*32] = __float2bfloat16(hv);
      if (last){
        hout_plain[(size_t)(r0 + lb*4 + r)*1024 + ucol] = hv;
        if (hbplain) hbplain[(size_t)(r0 + lb*4 + r)*1024 + ucol] = __float2bfloat16(hv);
      }
    }
    if (coop && t + 1 < nsteps){
      VMWAIT(0);          // all this thread's h stores are in L2
      __syncthreads();    // whole block's stores in L2
      if (tid == 0){
        __builtin_amdgcn_fence(__ATOMIC_RELEASE, "agent");   // one L2-wb per block per step
        __hip_atomic_store(&prog[bs*64 + ub], (unsigned)(t+1), __ATOMIC_RELAXED, __HIP_MEMORY_SCOPE_AGENT);
      }
    }
  }
}

// ---------------- pipelined generic GEMM: C[M,N] = A @ B^T (+bias/epilogue) ----------------
__global__ __launch_bounds__(256) void gemm64(
    const bf16* __restrict__ Am, const bf16* __restrict__ Bm, int K,
    const float* __restrict__ bias, const float* __restrict__ addmat,
    float* __restrict__ C, bf16* __restrict__ Cbf, int N, int MODE)
{
  __shared__ bf16 As[3][64*64];
  __shared__ bf16 Bs[3][64*64];
  const int tid = threadIdx.x;
  const int wave = tid >> 6, lane = tid & 63;
  const int m0 = blockIdx.x*64, n0 = blockIdx.y*64;
  const int fr = lane & 31, kh = lane >> 5;
  const int wm = (wave >> 1)*32, wn = (wave & 1)*32;
  const int KT = K >> 6;

  f32x16 acc = {0.f,0.f,0.f,0.f,0.f,0.f,0.f,0.f,0.f,0.f,0.f,0.f,0.f,0.f,0.f,0.f};

  auto STAGE = [&](int buf, int kt){
    #pragma unroll
    for (int q = 0; q < 2; ++q){
      int idx = q*256 + tid;
      int row = idx >> 3, cp = idx & 7, csw = cp ^ (row & 7);
      GLD16(&As[buf][idx*8], Am + (size_t)(m0+row)*K + kt*64 + csw*8);
    }
    #pragma unroll
    for (int q = 0; q < 2; ++q){
      int idx = q*256 + tid;
      int row = idx >> 3, cp = idx & 7, csw = cp ^ (row & 7);
      GLD16(&Bs[buf][idx*8], Bm + (size_t)(n0+row)*K + kt*64 + csw*8);
    }
  };
  auto COMPUTE = [&](int buf){
    const bf16* Ab = &As[buf][0];
    const bf16* Bb = &Bs[buf][0];
    #pragma unroll
    for (int ks = 0; ks < 4; ++ks){
      int ca = ks*2 + kh;
      v8bf av = *(const v8bf*)&Ab[(wm+fr)*64 + ((ca ^ ((wm+fr)&7))*8)];
      v8bf bv = *(const v8bf*)&Bb[(wn+fr)*64 + ((ca ^ ((wn+fr)&7))*8)];
      acc = __builtin_amdgcn_mfma_f32_32x32x16_bf16(av, bv, acc, 0, 0, 0);
    }
  };

  STAGE(0, 0);
  if (KT > 1){ STAGE(1, 1); VMWAIT(4); } else { VMWAIT(0); }
  BARRIER();
  for (int kt = 0; kt < KT; ++kt){
    if (kt + 2 < KT) STAGE((kt+2)%3, kt+2);
    COMPUTE(kt%3);
    if (kt + 2 < KT){ VMWAIT(4); BARRIER(); }
    else if (kt + 1 < KT){ VMWAIT(0); BARRIER(); }
  }

  const int col = n0 + wn + fr;
  float bb = bias ? bias[col] : 0.f;
  #pragma unroll
  for (int r = 0; r < 16; ++r){
    int row = m0 + wm + (r&3) + 8*(r>>2) + 4*kh;
    float v = acc[r] + bb;
    if (MODE == 1) v = fmaxf(v, 0.f) + addmat[(size_t)row*N + col];
    if (C)   C[(size_t)row*N + col] = v;
    if (Cbf) Cbf[(size_t)row*N + col] = __float2bfloat16(v);
  }
}

// ---------------- attention: one block per (b,h) ----------------
__global__ __launch_bounds__(256) void k_attn(const bf16* __restrict__ qkv,
                                              bf16* __restrict__ ctxbf){
  __shared__ char smem[65536];
  bf16* qs = (bf16*)smem;               // [64][256] swizzled
  bf16* ks = qs + 64*256;
  float* sc = (float*)smem;             // [64][65], reuse
  float* cs = (float*)(smem + 32768);
  const int h = blockIdx.x, b = blockIdx.y;
  const int tid = threadIdx.x, wave = tid >> 6, lane = tid & 63;
  const int fr = lane & 31, kh = lane >> 5;
  const int wm = (wave >> 1)*32, wn = (wave & 1)*32;

  #pragma unroll
  for (int i = 0; i < 8; ++i){
    int idx = i*256 + tid;
    int row = idx >> 5, cp = idx & 31, csw = cp ^ (row & 7);
    GLD16(&qs[idx*8], qkv + (size_t)(b*F_ + row)*3072 + h*DH_ + csw*8);
  }
  #pragma unroll
  for (int i = 0; i < 8; ++i){
    int idx = i*256 + tid;
    int row = idx >> 5, cp = idx & 31, csw = cp ^ (row & 7);
    GLD16(&ks[idx*8], qkv + (size_t)(b*F_ + row)*3072 + H_ + h*DH_ + csw*8);
  }
  __syncthreads();

  f32x16 acc = {0.f,0.f,0.f,0.f,0.f,0.f,0.f,0.f,0.f,0.f,0.f,0.f,0.f,0.f,0.f,0.f};
  #pragma unroll
  for (int i = 0; i < 16; ++i){
    int ca = i*2 + kh;
    v8bf av = *(const v8bf*)&qs[((wm+fr)*32 + (ca ^ ((wm+fr)&7)))*8];
    v8bf bv = *(const v8bf*)&ks[((wn+fr)*32 + (ca ^ ((wn+fr)&7)))*8];
    acc = __builtin_amdgcn_mfma_f32_32x32x16_bf16(av, bv, acc, 0, 0, 0);
  }
  __syncthreads();
  #pragma unroll
  for (int r = 0; r < 16; ++r){
    int row = wm + (r&3) + 8*(r>>2) + 4*kh;
    sc[row*65 + (wn+fr)] = acc[r]*0.0625f;
  }
  __syncthreads();
  if (tid < F_){
    float m = -1e30f;
    for (int k2 = 0; k2 < F_; ++k2) m = fmaxf(m, sc[tid*65+k2]);
    float s = 0.f;
    for (int k2 = 0; k2 < F_; ++k2){ float e = __expf(sc[tid*65+k2]-m); sc[tid*65+k2] = e; s += e; }
    float is = 1.f/s;
    for (int k2 = 0; k2 < F_; ++k2) sc[tid*65+k2] *= is;
  }
  __syncthreads();
  if (tid < F_){
    float s = 0.f;
    for (int r = 0; r < F_; ++r) s += sc[r*65+tid];
    cs[tid] = s;
  }
  __syncthreads();
  float a = 0.f;
  for (int k2 = 0; k2 < F_; ++k2){
    float v = __bfloat162float(qkv[(size_t)(b*F_+k2)*3072 + 2*H_ + h*DH_ + tid]);
    a += cs[k2]*v;
  }
  ctxbf[(size_t)b*H_ + h*DH_ + tid] = __float2bfloat16(a * (1.f/61.f));
}

// ---------------- SPL: parent chains + W2 head + x update ----------------
__constant__ int LVJ[14] = {0,1,6,8,9, 2,3,7,10,11, 4,5,12,13};
__constant__ int LVO[4]  = {0,5,10,14};
__constant__ int PAR_[14] = {-1,-1,0,1,2,3,-1,6,-1,-1,8,9,10,11};

__global__ __launch_bounds__(128) void spl_all(const float* __restrict__ hh_pre, const float* __restrict__ W1,
                        const float* __restrict__ W2, const float* __restrict__ b2,
                        float* __restrict__ x, bf16* __restrict__ xpk,
                        float* __restrict__ out, int tstep){
  __shared__ float preds_s[4][128];
  __shared__ float hh_s[128][5];
  int b0 = blockIdx.x*4, t = threadIdx.x;   // grid 64, block 128
  for (int L = 0; L < 3; ++L){
    for (int ji = LVO[L]; ji < LVO[L+1]; ++ji){
      int j = LVJ[ji], p = PAR_[j];
      float acc[4];
      #pragma unroll
      for (int bb = 0; bb < 4; ++bb) acc[bb] = hh_pre[(size_t)(b0+bb)*1792 + j*128 + t];
      if (p >= 0){
        #pragma unroll
        for (int ii = 0; ii < 9; ++ii){
          float w = W1[(size_t)(j*128 + t)*1033 + 1024 + ii];
          #pragma unroll
          for (int bb = 0; bb < 4; ++bb) acc[bb] += w * preds_s[bb][p*9 + ii];
        }
      }
      #pragma unroll
      for (int bb = 0; bb < 4; ++bb) hh_s[t][bb] = fmaxf(acc[bb], 0.f);
      __syncthreads();
      if (t < 72){
        int pp = t >> 1, half = t & 1;
        int bb = pp/9, oi = pp%9;
        const float* w2r = W2 + (size_t)(j*9 + oi)*128 + half*64;
        float s = 0.f;
        #pragma unroll
        for (int tt = 0; tt < 64; ++tt) s += hh_s[half*64 + tt][bb] * w2r[tt];
        s += __shfl_xor(s, 1);
        if (half == 0) preds_s[bb][j*9 + oi] = tanhf(s + b2[j*9 + oi]);
      }
      __syncthreads();
    }
  }
  for (int i = t; i < 4*D_; i += 128){
    int bb = i / D_, d = i % D_;
    int row = b0 + bb;
    size_t xi = (size_t)row*D_ + d;
    float v = x[xi] + preds_s[bb][d];
    x[xi] = v;
    xpk[((row>>5)*4 + (d>>5))*1024 + (row&31)*32 + (d&31)] = __float2bfloat16(v);
    out[((size_t)row*PRED_ + tstep)*D_ + d] = v;
  }
}

// ---------------- launch ----------------
extern "C" void kernel_launch(void* const* d_in, const int* in_sizes, int n_in,
                              void* d_out, int out_size, void* d_ws, size_t ws_size,
                              hipStream_t stream){
  (void)in_sizes; (void)n_in; (void)out_size; (void)ws_size;
  const float* poses = (const float*)d_in[0];
  const float* gWih  = (const float*)d_in[1];
  const float* gWhh  = (const float*)d_in[2];
  const float* gbih  = (const float*)d_in[3];
  const float* gbhh  = (const float*)d_in[4];
  const float* preW  = (const float*)d_in[5];
  const float* preb  = (const float*)d_in[6];
  const float* fpW   = (const float*)d_in[7];
  const float* fpb   = (const float*)d_in[8];
  const float* inW   = (const float*)d_in[9];
  const float* inb   = (const float*)d_in[10];
  const float* outW  = (const float*)d_in[11];
  const float* outb  = (const float*)d_in[12];
  const float* sW1   = (const float*)d_in[13];
  const float* sb1   = (const float*)d_in[14];
  const float* sW2   = (const float*)d_in[15];
  const float* sb2   = (const float*)d_in[16];
  float* out = (float*)d_out;

  char* w = (char*)d_ws;
  size_t off = 0;
  auto alloc = [&](size_t bytes)->char*{ char* p = w + off; off += (bytes + 255) & ~(size_t)255; return p; };
  float* cosT   = (float*)alloc(7320*4);
  float* bc     = (float*)alloc(3072*4);
  float* motion = (float*)alloc((size_t)256*1024*4);
  float* hA     = (float*)alloc((size_t)256*1024*4);
  float* hB     = (float*)alloc((size_t)256*1024*4);
  float* xcur   = (float*)alloc((size_t)256*126*4);
  float* hhpre  = (float*)alloc((size_t)256*1792*4);
  float* bcat   = (float*)alloc(4096*4);
  unsigned* prog= (unsigned*)alloc(1024);
  bf16* posespk = (bf16*)alloc((size_t)121*32768*2);   // +1 step pad for cross-step prefetch
  bf16* Wcat    = (bf16*)alloc((size_t)4096*1152*2);
  bf16* Wpk     = (bf16*)alloc((size_t)64*108*512*2);
  bf16* prebf   = (bf16*)alloc((size_t)1024*1024*2);
  bf16* outbf   = (bf16*)alloc((size_t)1024*1024*2);
  bf16* inbf    = (bf16*)alloc((size_t)3072*1024*2);
  bf16* fpwt    = (bf16*)alloc((size_t)128*1024*2);
  bf16* w1h     = (bf16*)alloc((size_t)1792*1024*2);
  bf16* ctxbf   = (bf16*)alloc((size_t)256*1024*2);
  bf16* hpkA    = (bf16*)alloc((size_t)256*1024*2);
  bf16* hpkB    = (bf16*)alloc((size_t)256*1024*2);
  bf16* hbplain = (bf16*)alloc((size_t)256*1024*2);
  bf16* xpk     = (bf16*)alloc((size_t)32768*2);
  bf16* hidbf   = (bf16*)alloc((size_t)256*1024*2);
  bf16* Wcbf    = (bf16*)alloc((size_t)3072*128*2);
  bf16* freqbf  = (bf16*)alloc((size_t)B_*F_*128*2);
  bf16* qkvbf   = (bf16*)alloc((size_t)15680*3072*2);

  hipMemsetAsync(hpkA, 0, (size_t)256*1024*2, stream);
  hipMemsetAsync(prog, 0, 1024, stream);

  k_cos<<<29, 256, 0, stream>>>(cosT);
  k_dft2<<<B_, 256, 0, stream>>>(poses, cosT, freqbf);
  c_poses<<<dim3(SEED_, B_), 128, 0, stream>>>(poses, posespk);
  c_xinit<<<B_, 128, 0, stream>>>(poses, xcur, xpk);
  c_wcat<<<4096, 256, 0, stream>>>(gWih, gWhh, Wcat);
  c_bcat<<<16, 256, 0, stream>>>(gbih, gbhh, bcat);
  c_wpk<<<1728, 256, 0, stream>>>(Wcat, Wpk);
  c_bf<<<4096, 256, 0, stream>>>(preW, prebf, 1024*1024);
  c_bf<<<4096, 256, 0, stream>>>(outW, outbf, 1024*1024);
  c_bf<<<12288, 256, 0, stream>>>(inW, inbf, 3072*1024);
  c_fpwt<<<128, 256, 0, stream>>>(fpW, fpwt);
  c_w1hid<<<7168, 256, 0, stream>>>(sW1, w1h);
  k_bc<<<768, 256, 0, stream>>>(inW, inb, fpb, bc);

  // Wc = inproj @ fp_W  (3072 x 128, bf16)
  gemm64<<<dim3(48, 2), 256, 0, stream>>>(inbf, fpwt, 1024, nullptr, nullptr, nullptr, Wcbf, 128, 0);
  // qkv = freq @ Wc^T + bc  (15616 x 3072, bf16)
  gemm64<<<dim3(244, 48), 256, 0, stream>>>(freqbf, Wcbf, 128, bc, nullptr, nullptr, qkvbf, 3072, 0);
  k_attn<<<dim3(HEADS_, B_), 256, 0, stream>>>(qkvbf, ctxbf);
  // motion_ctx = ctx_mean @ outproj^T + outb
  gemm64<<<dim3(4, 16), 256, 0, stream>>>(ctxbf, outbf, 1024, outb, nullptr, motion, nullptr, 1024, 0);

  // encoder: cooperative (co-residency), flag-synced, 120 steps;
  // final h -> hA (fp32 plain) + packed buffer (t=119 odd -> hpk0 = hpkA)
  {
    const bf16* a0 = posespk; int a1 = 32768; int a2 = SEED_; int a3 = 1;
    const bf16* a4 = Wpk; const float* a5 = bcat;
    const float* a6 = hA; float* a7 = hA; bf16* a8 = nullptr;
    bf16* a9 = hpkA; bf16* a10 = hpkB; unsigned* a11 = prog;
    void* args[] = { &a0, &a1, &a2, &a3, &a4, &a5, &a6, &a7, &a8, &a9, &a10, &a11 };
    hipLaunchCooperativeKernel(reinterpret_cast<void*>(gru_wave), dim3(128), dim3(512),
                               args, 0, stream);
  }

  float* hc = hA;  float* hn = hB;
  bf16* hpc = hpkA; bf16* hpn = hpkB;

  // decoder: 24 steps
  for (int t = 0; t < PRED_; ++t){
    gru_wave<<<128, 512, 0, stream>>>(xpk, 0, 1, 0, Wpk, bcat, hc, hn, hbplain, hpc, hpn, nullptr);
    { float* tf = hc; hc = hn; hn = tf; bf16* tb = hpc; hpc = hpn; hpn = tb; }
    gemm64<<<dim3(4, 16), 256, 0, stream>>>(hbplain, prebf, 1024, preb, motion, nullptr, hidbf, 1024, 1);
    gemm64<<<dim3(4, 28), 256, 0, stream>>>(hidbf, w1h, 1024, sb1, nullptr, hhpre, nullptr, 1792, 0);
    spl_all<<<64, 128, 0, stream>>>(hhpre, sW1, sW2, sb2, xcur, xpk, out, t);
  }
}

// Round 10
// 3686.340 us; speedup vs baseline: 1.5818x; 1.1776x over previous
//
#include <hip/hip_runtime.h>
#include <hip/hip_bf16.h>

typedef __hip_bfloat16 bf16;
typedef __attribute__((ext_vector_type(8))) short v8bf;     // 8 bf16 (4 VGPR)
typedef __attribute__((ext_vector_type(16))) float f32x16;
typedef __attribute__((ext_vector_type(4))) float f32x4;
typedef unsigned long long ull;

#define B_    256
#define SEED_ 120
#define PRED_ 24
#define D_    126
#define H_    1024
#define F_    61
#define HEADS_ 4
#define DH_   256

#define GLD16(lds, g) __builtin_amdgcn_global_load_lds( \
    (const __attribute__((address_space(1))) unsigned int*)(g), \
    (__attribute__((address_space(3))) unsigned int*)(lds), 16, 0, 0)
#define VMWAIT(n) asm volatile("s_waitcnt vmcnt(" #n ")" ::: "memory")
#define BARRIER() do { __builtin_amdgcn_s_barrier(); __builtin_amdgcn_sched_barrier(0); } while(0)

// ---------------- small precompute kernels ----------------
__global__ void k_cos(float* cosT){
  int i = blockIdx.x*256 + threadIdx.x;
  if (i < F_*SEED_){
    int f = i / SEED_, t = i % SEED_;
    int ph = (f*t) % SEED_;
    cosT[i] = cosf(6.283185307179586f * (float)ph / (float)SEED_);
  }
}

// one block per b; poses row staged once in LDS; 31 f-accumulators per thread.
__global__ __launch_bounds__(256) void k_dft2(const float* __restrict__ poses,
                      const float* __restrict__ cosT, bf16* __restrict__ freqbf){
  __shared__ float pl[SEED_*128];      // 60 KB
  int b = blockIdx.x, tid = threadIdx.x;
  for (int i = tid; i < SEED_*D_; i += 256){
    int t = i / D_, d = i - t*D_;
    pl[t*128 + d] = poses[((size_t)b*(SEED_+PRED_) + t)*D_ + d];
  }
  __syncthreads();
  int d = tid & 127, f0 = tid >> 7;    // f = f0 + 2j
  float acc[31];
  #pragma unroll
  for (int j = 0; j < 31; ++j) acc[j] = 0.f;
  for (int t = 0; t < SEED_; ++t){
    float v = pl[t*128 + d];
    #pragma unroll
    for (int j = 0; j < 31; ++j){
      int f = f0 + j*2;
      if (f < F_) acc[j] += cosT[f*SEED_ + t] * v;
    }
  }
  #pragma unroll
  for (int j = 0; j < 31; ++j){
    int f = f0 + j*2;
    if (f < F_) freqbf[((size_t)b*F_ + f)*128 + d] = __float2bfloat16(d < D_ ? acc[j] : 0.f);
  }
}

// pack poses into per-step 32x32 tiles: pk[t][ (b>>5)*4 + (c>>5) ][ (b&31)*32 + (c&31) ]
__global__ void c_poses(const float* __restrict__ poses, bf16* __restrict__ pk){
  int t = blockIdx.x, b = blockIdx.y, c = threadIdx.x;  // block 128
  float v = (c < D_) ? poses[((size_t)b*(SEED_+PRED_) + t)*D_ + c] : 0.f;
  pk[(size_t)t*32768 + ((b>>5)*4 + (c>>5))*1024 + (b&31)*32 + (c&31)] = __float2bfloat16(v);
}

__global__ void c_xinit(const float* __restrict__ poses, float* __restrict__ x, bf16* __restrict__ xpk){
  int b = blockIdx.x, c = threadIdx.x;  // block 128
  float v = (c < D_) ? poses[((size_t)b*(SEED_+PRED_) + (SEED_-1))*D_ + c] : 0.f;
  if (c < D_) x[b*D_ + c] = v;
  xpk[((b>>5)*4 + (c>>5))*1024 + (b&31)*32 + (c&31)] = __float2bfloat16(v);
}

__global__ void c_bf(const float* __restrict__ s, bf16* __restrict__ d, int n){
  int i = blockIdx.x*256 + threadIdx.x;
  if (i < n) d[i] = __float2bfloat16(s[i]);
}

__global__ void c_fpwt(const float* __restrict__ fpW, bf16* __restrict__ o){
  int dd = blockIdx.x;                       // 0..127
  for (int k = threadIdx.x; k < H_; k += 256)
    o[(size_t)dd*H_ + k] = __float2bfloat16(dd < D_ ? fpW[(size_t)k*D_ + dd] : 0.f);
}

__global__ void c_w1hid(const float* __restrict__ W1, bf16* __restrict__ o){
  int i = blockIdx.x*256 + threadIdx.x;      // 1792*1024
  if (i < 1792*1024){ int r = i >> 10, c = i & 1023; o[i] = __float2bfloat16(W1[(size_t)r*1033 + c]); }
}

// combined GRU weight: rows 0..1023=[Wih_r|Whh_r]; 1024..2047=[Wih_z|Whh_z];
// 2048..3071=[Wih_n|0]; 3072..4095=[0|Whh_n]  (row width 1152 = 128 x | 1024 h)
__global__ void c_wcat(const float* __restrict__ Wih, const float* __restrict__ Whh, bf16* __restrict__ o){
  int r = blockIdx.x;
  int jr; bool hasx, hash;
  if (r < 2048){ jr = r; hasx = true; hash = true; }
  else if (r < 3072){ jr = r; hasx = true; hash = false; }
  else { jr = r - 1024; hasx = false; hash = true; }
  bf16* row = o + (size_t)r*1152;
  for (int c = threadIdx.x; c < 1152; c += 256){
    float v = 0.f;
    if (c < D_) { if (hasx) v = Wih[(size_t)jr*D_ + c]; }
    else if (c >= 128){ if (hash) v = Whh[(size_t)jr*H_ + (c-128)]; }
    row[c] = __float2bfloat16(v);
  }
}

__global__ void c_bcat(const float* __restrict__ bih, const float* __restrict__ bhh, float* __restrict__ o){
  int r = blockIdx.x*256 + threadIdx.x;
  if (r >= 4096) return;
  float v;
  if (r < 2048) v = bih[r] + bhh[r];
  else if (r < 3072) v = bih[r];
  else v = bhh[r - 1024];
  o[r] = v;
}

// pack GRU weights into MFMA B-fragment order:
// chunk = ((ub*3+g)*36+ks): elem[l*8+e] = W_g[ub*16+(l&15)][ks*32+(l>>4)*8+e]
__global__ __launch_bounds__(256) void c_wpk(const bf16* __restrict__ Wcat, bf16* __restrict__ Wpk){
  int chunk = blockIdx.x*4 + (threadIdx.x >> 6);
  int l = threadIdx.x & 63;
  int ks = chunk % 36; int t2 = chunk / 36; int g = t2 % 3; int ub = t2 / 3;
  int unit = ub*16 + (l & 15);
  bf16* dst = Wpk + (size_t)chunk*512 + l*8;
  #pragma unroll
  for (int e = 0; e < 8; ++e){
    int k = ks*32 + (l>>4)*8 + e;
    int row = (g==0) ? unit : (g==1) ? (1024+unit) : (k < 128 ? 2048+unit : 3072+unit);
    dst[e] = Wcat[(size_t)row*1152 + k];
  }
}

// bc = inproj @ fp_b + in_b : wave-per-row float4 reduction. grid 768, block 256.
__global__ __launch_bounds__(256) void k_bc(const float* __restrict__ inW, const float* __restrict__ inb,
                     const float* __restrict__ fpb, float* __restrict__ bc){
  int wave = threadIdx.x >> 6, lane = threadIdx.x & 63;
  int r = blockIdx.x*4 + wave;
  const float4* row = (const float4*)(inW + (size_t)r*H_);
  const float4* fp4 = (const float4*)fpb;
  float s = 0.f;
  #pragma unroll
  for (int i = 0; i < 4; ++i){
    float4 a = row[lane + i*64];
    float4 b = fp4[lane + i*64];
    s += a.x*b.x + a.y*b.y + a.z*b.z + a.w*b.w;
  }
  #pragma unroll
  for (int off = 32; off; off >>= 1) s += __shfl_down(s, off);
  if (lane == 0) bc[r] = s + inb[r];
}

// ---------------- wave-autonomous GRU, fence-free coherent h path ----------------
// grid 128 = 64 unit-slices x 2 batch-halves; block 512 (8 waves x 16 rows).
// Weights LDS-resident (108KB). h ping-pong moves through the COHERENT POINT (IF):
// all h loads/stores are relaxed agent-scope atomics (bypass per-XCD L2) -> no
// release-writeback / acquire-invalidate fences anywhere in the step loop.
// x (read-only) and weights stay normally cached. Ring of 12 slices x 2x8B.
#define SLCP(QA, QB, KS, GACC) { \
  union { ull u[2]; v8bf v; } cc_; cc_.u[0]=(QA); cc_.u[1]=(QB); \
  v8bf a_ = cc_.v; \
  v8bf w0_ = *(const v8bf*)&Wl[(0*36+(KS))*512 + lane*8]; \
  v8bf w1_ = *(const v8bf*)&Wl[(1*36+(KS))*512 + lane*8]; \
  v8bf w2_ = *(const v8bf*)&Wl[(2*36+(KS))*512 + lane*8]; \
  aR = __builtin_amdgcn_mfma_f32_16x16x32_bf16(a_, w0_, aR, 0,0,0); \
  aZ = __builtin_amdgcn_mfma_f32_16x16x32_bf16(a_, w1_, aZ, 0,0,0); \
  GACC = __builtin_amdgcn_mfma_f32_16x16x32_bf16(a_, w2_, GACC, 0,0,0); }

#define LDHA(DA, DB, C) { \
  const ull* hp_ = (const ull*)(hs + hbase + (size_t)(C)*1024); \
  DA = __hip_atomic_load(hp_,   __ATOMIC_RELAXED, __HIP_MEMORY_SCOPE_AGENT); \
  DB = __hip_atomic_load(hp_+1, __ATOMIC_RELAXED, __HIP_MEMORY_SCOPE_AGENT); }

#define LDXP(DA, DB, TT, C) { \
  const ull* xp_ = (const ull*)(xpk + (size_t)(TT)*xstride + xbase + (size_t)(C)*1024); \
  DA = xp_[0]; DB = xp_[1]; }

__global__ __launch_bounds__(512) void gru_wave(
    const bf16* __restrict__ xpk, int xstride, int nsteps, int coop,
    const bf16* __restrict__ Wpk, const float* __restrict__ bcat,
    const float* __restrict__ hin_plain, float* __restrict__ hout_plain,
    bf16* __restrict__ hbplain,
    bf16* __restrict__ hpk0, bf16* __restrict__ hpk1,
    unsigned* __restrict__ prog)
{
  __shared__ bf16 Wl[3*36*512];       // 108 KB
  const int tid = threadIdx.x, wave = tid >> 6, lane = tid & 63;
  const int ub = blockIdx.x >> 1, bs = blockIdx.x & 1;
  const int u0 = ub*16;

  {  // weights -> LDS once
    const bf16* wsrc = Wpk + (size_t)ub*(3*36*512);
    #pragma unroll
    for (int i = 0; i < 14; ++i){
      int c = i*512 + tid;
      if (c < 6912) GLD16(&Wl[c*8], wsrc + (size_t)c*8);
    }
  }
  VMWAIT(0); BARRIER();

  const int la = lane & 15, lb = lane >> 4;
  const int r0 = bs*128 + wave*16;
  const int rb = r0 >> 5, y = wave & 1;
  const int ucol = u0 + la;
  const float bR = bcat[ucol], bZ = bcat[1024+ucol], bI = bcat[2048+ucol], bN = bcat[3072+ucol];
  const size_t hbase = (size_t)rb*32768 + (size_t)y*512 + la*32 + lb*8;
  const size_t xbase = (size_t)rb*4096  + (size_t)y*512 + la*32 + lb*8;
  // packed write base: tile (rb, u0>>5), row-in-tile = y*16 + lb*4 + rr, col-in-tile = (u0&16)+la
  const size_t pwb = (size_t)rb*32768 + (size_t)(u0>>5)*1024 + (size_t)y*512 + (u0&16) + la;

  float hr[4];
  if (nsteps == 1){
    #pragma unroll
    for (int r = 0; r < 4; ++r) hr[r] = hin_plain[(size_t)(r0 + lb*4 + r)*1024 + ucol];
  } else {
    #pragma unroll
    for (int r = 0; r < 4; ++r) hr[r] = 0.f;
  }

  ull a0,a1,a2,a3,a4,a5,a6,a7,a8,a9,a10,a11;
  ull b0,b1,b2,b3,b4,b5,b6,b7,b8,b9,b10,b11;
  LDXP(a0,b0,0,0); LDXP(a1,b1,0,1); LDXP(a2,b2,0,2); LDXP(a3,b3,0,3);

  for (int t = 0; t < nsteps; ++t){
    if (coop && t > 0){
      if (wave == 0){
        unsigned v = __hip_atomic_load(&prog[bs*64 + lane], __ATOMIC_RELAXED, __HIP_MEMORY_SCOPE_AGENT);
        while (__ballot(v >= (unsigned)t) != ~0ULL){
          __builtin_amdgcn_s_sleep(1);
          v = __hip_atomic_load(&prog[bs*64 + lane], __ATOMIC_RELAXED, __HIP_MEMORY_SCOPE_AGENT);
        }
      }
      __syncthreads();
      __builtin_amdgcn_sched_barrier(0);
    }
    const bf16* hs = (t & 1) ? hpk1 : hpk0;
    LDHA(a4,b4,0) LDHA(a5,b5,1) LDHA(a6,b6,2) LDHA(a7,b7,3)
    LDHA(a8,b8,4) LDHA(a9,b9,5) LDHA(a10,b10,6) LDHA(a11,b11,7)

    f32x4 z4 = {0.f,0.f,0.f,0.f};
    f32x4 aR = z4, aZ = z4, aI = z4, aN = z4;

    SLCP(a0,b0,0,aI)  LDHA(a0,b0,8)
    SLCP(a1,b1,1,aI)  LDHA(a1,b1,9)
    SLCP(a2,b2,2,aI)  LDHA(a2,b2,10)
    SLCP(a3,b3,3,aI)  LDHA(a3,b3,11)
    SLCP(a4,b4,4,aN)  LDHA(a4,b4,12)
    SLCP(a5,b5,5,aN)  LDHA(a5,b5,13)
    SLCP(a6,b6,6,aN)  LDHA(a6,b6,14)
    SLCP(a7,b7,7,aN)  LDHA(a7,b7,15)
    SLCP(a8,b8,8,aN)  LDHA(a8,b8,16)
    SLCP(a9,b9,9,aN)  LDHA(a9,b9,17)
    SLCP(a10,b10,10,aN) LDHA(a10,b10,18)
    SLCP(a11,b11,11,aN) LDHA(a11,b11,19)
    SLCP(a0,b0,12,aN) LDHA(a0,b0,20)
    SLCP(a1,b1,13,aN) LDHA(a1,b1,21)
    SLCP(a2,b2,14,aN) LDHA(a2,b2,22)
    SLCP(a3,b3,15,aN) LDHA(a3,b3,23)
    SLCP(a4,b4,16,aN) LDHA(a4,b4,24)
    SLCP(a5,b5,17,aN) LDHA(a5,b5,25)
    SLCP(a6,b6,18,aN) LDHA(a6,b6,26)
    SLCP(a7,b7,19,aN) LDHA(a7,b7,27)
    SLCP(a8,b8,20,aN) LDHA(a8,b8,28)
    SLCP(a9,b9,21,aN) LDHA(a9,b9,29)
    SLCP(a10,b10,22,aN) LDHA(a10,b10,30)
    SLCP(a11,b11,23,aN) LDHA(a11,b11,31)
    SLCP(a0,b0,24,aN) LDXP(a0,b0,t+1,0)
    SLCP(a1,b1,25,aN) LDXP(a1,b1,t+1,1)
    SLCP(a2,b2,26,aN) LDXP(a2,b2,t+1,2)
    SLCP(a3,b3,27,aN) LDXP(a3,b3,t+1,3)
    SLCP(a4,b4,28,aN)
    SLCP(a5,b5,29,aN)
    SLCP(a6,b6,30,aN)
    SLCP(a7,b7,31,aN)
    SLCP(a8,b8,32,aN)
    SLCP(a9,b9,33,aN)
    SLCP(a10,b10,34,aN)
    SLCP(a11,b11,35,aN)

    bf16* hd = (t & 1) ? hpk0 : hpk1;
    const bool last = (t == nsteps-1);
    #pragma unroll
    for (int r = 0; r < 4; ++r){
      float rg = 1.f/(1.f + __expf(-(aR[r] + bR)));
      float zg = 1.f/(1.f + __expf(-(aZ[r] + bZ)));
      float ng = tanhf((aI[r] + bI) + rg*(aN[r] + bN));
      float hv = (1.f - zg)*ng + zg*hr[r];
      hr[r] = hv;
      bf16 hv16 = __float2bfloat16(hv);
      unsigned short hbits = *(unsigned short*)&hv16;
      __hip_atomic_store((unsigned short*)(hd + pwb + (size_t)(lb*4 + r)*32), hbits,
                         __ATOMIC_RELAXED, __HIP_MEMORY_SCOPE_AGENT);
      if (last){
        hout_plain[(size_t)(r0 + lb*4 + r)*1024 + ucol] = hv;
        if (hbplain) hbplain[(size_t)(r0 + lb*4 + r)*1024 + ucol] = __float2bfloat16(hv);
      }
    }
    if (coop && t + 1 < nsteps){
      VMWAIT(0);          // h atomic stores committed at the coherent point
      __syncthreads();    // whole block done
      if (tid == 0)
        __hip_atomic_store(&prog[bs*64 + ub], (unsigned)(t+1), __ATOMIC_RELAXED, __HIP_MEMORY_SCOPE_AGENT);
    }
  }
}

// ---------------- pipelined generic GEMM: C[M,N] = A @ B^T (+bias/epilogue) ----------------
__global__ __launch_bounds__(256) void gemm64(
    const bf16* __restrict__ Am, const bf16* __restrict__ Bm, int K,
    const float* __restrict__ bias, const float* __restrict__ addmat,
    float* __restrict__ C, bf16* __restrict__ Cbf, int N, int MODE)
{
  __shared__ bf16 As[3][64*64];
  __shared__ bf16 Bs[3][64*64];
  const int tid = threadIdx.x;
  const int wave = tid >> 6, lane = tid & 63;
  const int m0 = blockIdx.x*64, n0 = blockIdx.y*64;
  const int fr = lane & 31, kh = lane >> 5;
  const int wm = (wave >> 1)*32, wn = (wave & 1)*32;
  const int KT = K >> 6;

  f32x16 acc = {0.f,0.f,0.f,0.f,0.f,0.f,0.f,0.f,0.f,0.f,0.f,0.f,0.f,0.f,0.f,0.f};

  auto STAGE = [&](int buf, int kt){
    #pragma unroll
    for (int q = 0; q < 2; ++q){
      int idx = q*256 + tid;
      int row = idx >> 3, cp = idx & 7, csw = cp ^ (row & 7);
      GLD16(&As[buf][idx*8], Am + (size_t)(m0+row)*K + kt*64 + csw*8);
    }
    #pragma unroll
    for (int q = 0; q < 2; ++q){
      int idx = q*256 + tid;
      int row = idx >> 3, cp = idx & 7, csw = cp ^ (row & 7);
      GLD16(&Bs[buf][idx*8], Bm + (size_t)(n0+row)*K + kt*64 + csw*8);
    }
  };
  auto COMPUTE = [&](int buf){
    const bf16* Ab = &As[buf][0];
    const bf16* Bb = &Bs[buf][0];
    #pragma unroll
    for (int ks = 0; ks < 4; ++ks){
      int ca = ks*2 + kh;
      v8bf av = *(const v8bf*)&Ab[(wm+fr)*64 + ((ca ^ ((wm+fr)&7))*8)];
      v8bf bv = *(const v8bf*)&Bb[(wn+fr)*64 + ((ca ^ ((wn+fr)&7))*8)];
      acc = __builtin_amdgcn_mfma_f32_32x32x16_bf16(av, bv, acc, 0, 0, 0);
    }
  };

  STAGE(0, 0);
  if (KT > 1){ STAGE(1, 1); VMWAIT(4); } else { VMWAIT(0); }
  BARRIER();
  for (int kt = 0; kt < KT; ++kt){
    if (kt + 2 < KT) STAGE((kt+2)%3, kt+2);
    COMPUTE(kt%3);
    if (kt + 2 < KT){ VMWAIT(4); BARRIER(); }
    else if (kt + 1 < KT){ VMWAIT(0); BARRIER(); }
  }

  const int col = n0 + wn + fr;
  float bb = bias ? bias[col] : 0.f;
  #pragma unroll
  for (int r = 0; r < 16; ++r){
    int row = m0 + wm + (r&3) + 8*(r>>2) + 4*kh;
    float v = acc[r] + bb;
    if (MODE == 1) v = fmaxf(v, 0.f) + addmat[(size_t)row*N + col];
    if (C)   C[(size_t)row*N + col] = v;
    if (Cbf) Cbf[(size_t)row*N + col] = __float2bfloat16(v);
  }
}

// ---------------- attention: one block per (b,h) ----------------
__global__ __launch_bounds__(256) void k_attn(const bf16* __restrict__ qkv,
                                              bf16* __restrict__ ctxbf){
  __shared__ char smem[65536];
  bf16* qs = (bf16*)smem;               // [64][256] swizzled
  bf16* ks = qs + 64*256;
  float* sc = (float*)smem;             // [64][65], reuse
  float* cs = (float*)(smem + 32768);
  const int h = blockIdx.x, b = blockIdx.y;
  const int tid = threadIdx.x, wave = tid >> 6, lane = tid & 63;
  const int fr = lane & 31, kh = lane >> 5;
  const int wm = (wave >> 1)*32, wn = (wave & 1)*32;

  #pragma unroll
  for (int i = 0; i < 8; ++i){
    int idx = i*256 + tid;
    int row = idx >> 5, cp = idx & 31, csw = cp ^ (row & 7);
    GLD16(&qs[idx*8], qkv + (size_t)(b*F_ + row)*3072 + h*DH_ + csw*8);
  }
  #pragma unroll
  for (int i = 0; i < 8; ++i){
    int idx = i*256 + tid;
    int row = idx >> 5, cp = idx & 31, csw = cp ^ (row & 7);
    GLD16(&ks[idx*8], qkv + (size_t)(b*F_ + row)*3072 + H_ + h*DH_ + csw*8);
  }
  __syncthreads();

  f32x16 acc = {0.f,0.f,0.f,0.f,0.f,0.f,0.f,0.f,0.f,0.f,0.f,0.f,0.f,0.f,0.f,0.f};
  #pragma unroll
  for (int i = 0; i < 16; ++i){
    int ca = i*2 + kh;
    v8bf av = *(const v8bf*)&qs[((wm+fr)*32 + (ca ^ ((wm+fr)&7)))*8];
    v8bf bv = *(const v8bf*)&ks[((wn+fr)*32 + (ca ^ ((wn+fr)&7)))*8];
    acc = __builtin_amdgcn_mfma_f32_32x32x16_bf16(av, bv, acc, 0, 0, 0);
  }
  __syncthreads();
  #pragma unroll
  for (int r = 0; r < 16; ++r){
    int row = wm + (r&3) + 8*(r>>2) + 4*kh;
    sc[row*65 + (wn+fr)] = acc[r]*0.0625f;
  }
  __syncthreads();
  if (tid < F_){
    float m = -1e30f;
    for (int k2 = 0; k2 < F_; ++k2) m = fmaxf(m, sc[tid*65+k2]);
    float s = 0.f;
    for (int k2 = 0; k2 < F_; ++k2){ float e = __expf(sc[tid*65+k2]-m); sc[tid*65+k2] = e; s += e; }
    float is = 1.f/s;
    for (int k2 = 0; k2 < F_; ++k2) sc[tid*65+k2] *= is;
  }
  __syncthreads();
  if (tid < F_){
    float s = 0.f;
    for (int r = 0; r < F_; ++r) s += sc[r*65+tid];
    cs[tid] = s;
  }
  __syncthreads();
  float a = 0.f;
  for (int k2 = 0; k2 < F_; ++k2){
    float v = __bfloat162float(qkv[(size_t)(b*F_+k2)*3072 + 2*H_ + h*DH_ + tid]);
    a += cs[k2]*v;
  }
  ctxbf[(size_t)b*H_ + h*DH_ + tid] = __float2bfloat16(a * (1.f/61.f));
}

// ---------------- SPL: parent chains + W2 head + x update ----------------
__constant__ int LVJ[14] = {0,1,6,8,9, 2,3,7,10,11, 4,5,12,13};
__constant__ int LVO[4]  = {0,5,10,14};
__constant__ int PAR_[14] = {-1,-1,0,1,2,3,-1,6,-1,-1,8,9,10,11};

__global__ __launch_bounds__(128) void spl_all(const float* __restrict__ hh_pre, const float* __restrict__ W1,
                        const float* __restrict__ W2, const float* __restrict__ b2,
                        float* __restrict__ x, bf16* __restrict__ xpk,
                        float* __restrict__ out, int tstep){
  __shared__ float preds_s[4][128];
  __shared__ float hh_s[128][5];
  int b0 = blockIdx.x*4, t = threadIdx.x;   // grid 64, block 128
  for (int L = 0; L < 3; ++L){
    for (int ji = LVO[L]; ji < LVO[L+1]; ++ji){
      int j = LVJ[ji], p = PAR_[j];
      float acc[4];
      #pragma unroll
      for (int bb = 0; bb < 4; ++bb) acc[bb] = hh_pre[(size_t)(b0+bb)*1792 + j*128 + t];
      if (p >= 0){
        #pragma unroll
        for (int ii = 0; ii < 9; ++ii){
          float w = W1[(size_t)(j*128 + t)*1033 + 1024 + ii];
          #pragma unroll
          for (int bb = 0; bb < 4; ++bb) acc[bb] += w * preds_s[bb][p*9 + ii];
        }
      }
      #pragma unroll
      for (int bb = 0; bb < 4; ++bb) hh_s[t][bb] = fmaxf(acc[bb], 0.f);
      __syncthreads();
      if (t < 72){
        int pp = t >> 1, half = t & 1;
        int bb = pp/9, oi = pp%9;
        const float* w2r = W2 + (size_t)(j*9 + oi)*128 + half*64;
        float s = 0.f;
        #pragma unroll
        for (int tt = 0; tt < 64; ++tt) s += hh_s[half*64 + tt][bb] * w2r[tt];
        s += __shfl_xor(s, 1);
        if (half == 0) preds_s[bb][j*9 + oi] = tanhf(s + b2[j*9 + oi]);
      }
      __syncthreads();
    }
  }
  for (int i = t; i < 4*D_; i += 128){
    int bb = i / D_, d = i % D_;
    int row = b0 + bb;
    size_t xi = (size_t)row*D_ + d;
    float v = x[xi] + preds_s[bb][d];
    x[xi] = v;
    xpk[((row>>5)*4 + (d>>5))*1024 + (row&31)*32 + (d&31)] = __float2bfloat16(v);
    out[((size_t)row*PRED_ + tstep)*D_ + d] = v;
  }
}

// ---------------- launch ----------------
extern "C" void kernel_launch(void* const* d_in, const int* in_sizes, int n_in,
                              void* d_out, int out_size, void* d_ws, size_t ws_size,
                              hipStream_t stream){
  (void)in_sizes; (void)n_in; (void)out_size; (void)ws_size;
  const float* poses = (const float*)d_in[0];
  const float* gWih  = (const float*)d_in[1];
  const float* gWhh  = (const float*)d_in[2];
  const float* gbih  = (const float*)d_in[3];
  const float* gbhh  = (const float*)d_in[4];
  const float* preW  = (const float*)d_in[5];
  const float* preb  = (const float*)d_in[6];
  const float* fpW   = (const float*)d_in[7];
  const float* fpb   = (const float*)d_in[8];
  const float* inW   = (const float*)d_in[9];
  const float* inb   = (const float*)d_in[10];
  const float* outW  = (const float*)d_in[11];
  const float* outb  = (const float*)d_in[12];
  const float* sW1   = (const float*)d_in[13];
  const float* sb1   = (const float*)d_in[14];
  const float* sW2   = (const float*)d_in[15];
  const float* sb2   = (const float*)d_in[16];
  float* out = (float*)d_out;

  char* w = (char*)d_ws;
  size_t off = 0;
  auto alloc = [&](size_t bytes)->char*{ char* p = w + off; off += (bytes + 255) & ~(size_t)255; return p; };
  float* cosT   = (float*)alloc(7320*4);
  float* bc     = (float*)alloc(3072*4);
  float* motion = (float*)alloc((size_t)256*1024*4);
  float* hA     = (float*)alloc((size_t)256*1024*4);
  float* hB     = (float*)alloc((size_t)256*1024*4);
  float* xcur   = (float*)alloc((size_t)256*126*4);
  float* hhpre  = (float*)alloc((size_t)256*1792*4);
  float* bcat   = (float*)alloc(4096*4);
  unsigned* prog= (unsigned*)alloc(1024);
  bf16* posespk = (bf16*)alloc((size_t)121*32768*2);   // +1 step pad for cross-step prefetch
  bf16* Wcat    = (bf16*)alloc((size_t)4096*1152*2);
  bf16* Wpk     = (bf16*)alloc((size_t)64*108*512*2);
  bf16* prebf   = (bf16*)alloc((size_t)1024*1024*2);
  bf16* outbf   = (bf16*)alloc((size_t)1024*1024*2);
  bf16* inbf    = (bf16*)alloc((size_t)3072*1024*2);
  bf16* fpwt    = (bf16*)alloc((size_t)128*1024*2);
  bf16* w1h     = (bf16*)alloc((size_t)1792*1024*2);
  bf16* ctxbf   = (bf16*)alloc((size_t)256*1024*2);
  bf16* hpkA    = (bf16*)alloc((size_t)256*1024*2);
  bf16* hpkB    = (bf16*)alloc((size_t)256*1024*2);
  bf16* hbplain = (bf16*)alloc((size_t)256*1024*2);
  bf16* xpk     = (bf16*)alloc((size_t)32768*2);
  bf16* hidbf   = (bf16*)alloc((size_t)256*1024*2);
  bf16* Wcbf    = (bf16*)alloc((size_t)3072*128*2);
  bf16* freqbf  = (bf16*)alloc((size_t)B_*F_*128*2);
  bf16* qkvbf   = (bf16*)alloc((size_t)15680*3072*2);

  hipMemsetAsync(hpkA, 0, (size_t)256*1024*2, stream);
  hipMemsetAsync(prog, 0, 1024, stream);

  k_cos<<<29, 256, 0, stream>>>(cosT);
  k_dft2<<<B_, 256, 0, stream>>>(poses, cosT, freqbf);
  c_poses<<<dim3(SEED_, B_), 128, 0, stream>>>(poses, posespk);
  c_xinit<<<B_, 128, 0, stream>>>(poses, xcur, xpk);
  c_wcat<<<4096, 256, 0, stream>>>(gWih, gWhh, Wcat);
  c_bcat<<<16, 256, 0, stream>>>(gbih, gbhh, bcat);
  c_wpk<<<1728, 256, 0, stream>>>(Wcat, Wpk);
  c_bf<<<4096, 256, 0, stream>>>(preW, prebf, 1024*1024);
  c_bf<<<4096, 256, 0, stream>>>(outW, outbf, 1024*1024);
  c_bf<<<12288, 256, 0, stream>>>(inW, inbf, 3072*1024);
  c_fpwt<<<128, 256, 0, stream>>>(fpW, fpwt);
  c_w1hid<<<7168, 256, 0, stream>>>(sW1, w1h);
  k_bc<<<768, 256, 0, stream>>>(inW, inb, fpb, bc);

  // Wc = inproj @ fp_W  (3072 x 128, bf16)
  gemm64<<<dim3(48, 2), 256, 0, stream>>>(inbf, fpwt, 1024, nullptr, nullptr, nullptr, Wcbf, 128, 0);
  // qkv = freq @ Wc^T + bc  (15616 x 3072, bf16)
  gemm64<<<dim3(244, 48), 256, 0, stream>>>(freqbf, Wcbf, 128, bc, nullptr, nullptr, qkvbf, 3072, 0);
  k_attn<<<dim3(HEADS_, B_), 256, 0, stream>>>(qkvbf, ctxbf);
  // motion_ctx = ctx_mean @ outproj^T + outb
  gemm64<<<dim3(4, 16), 256, 0, stream>>>(ctxbf, outbf, 1024, outb, nullptr, motion, nullptr, 1024, 0);

  // encoder: cooperative (co-residency), fence-free coherent h, 120 steps;
  // final h -> hA (fp32 plain); packed final lands in hpk0 = hpkA (t=119 odd)
  {
    const bf16* a0 = posespk; int a1 = 32768; int a2 = SEED_; int a3 = 1;
    const bf16* a4 = Wpk; const float* a5 = bcat;
    const float* a6 = hA; float* a7 = hA; bf16* a8 = nullptr;
    bf16* a9 = hpkA; bf16* a10 = hpkB; unsigned* a11 = prog;
    void* args[] = { &a0, &a1, &a2, &a3, &a4, &a5, &a6, &a7, &a8, &a9, &a10, &a11 };
    hipLaunchCooperativeKernel(reinterpret_cast<void*>(gru_wave), dim3(128), dim3(512),
                               args, 0, stream);
  }

  float* hc = hA;  float* hn = hB;
  bf16* hpc = hpkA; bf16* hpn = hpkB;

  // decoder: 24 steps
  for (int t = 0; t < PRED_; ++t){
    gru_wave<<<128, 512, 0, stream>>>(xpk, 0, 1, 0, Wpk, bcat, hc, hn, hbplain, hpc, hpn, nullptr);
    { float* tf = hc; hc = hn; hn = tf; bf16* tb = hpc; hpc = hpn; hpn = tb; }
    gemm64<<<dim3(4, 16), 256, 0, stream>>>(hbplain, prebf, 1024, preb, motion, nullptr, hidbf, 1024, 1);
    gemm64<<<dim3(4, 28), 256, 0, stream>>>(hidbf, w1h, 1024, sb1, nullptr, hhpre, nullptr, 1792, 0);
    spl_all<<<64, 128, 0, stream>>>(hhpre, sW1, sW2, sb2, xcur, xpk, out, t);
  }
}